// Round 1
// 238.496 us; speedup vs baseline: 1.0130x; 1.0130x over previous
//
#include <hip/hip_runtime.h>
#include <hip/hip_bf16.h>

// Problem constants
#define NN  50000   // nodes
#define FD  128     // features
#define NE  800000  // external edges
#define NEI 400000  // internal edges
#define NG  64      // graphs

// Workspace layout (bytes). [0, ZERO_BYTES) is zeroed each launch.
#define DEG_EXT_OFF 0        // 50000 int
#define DEG_INT_OFF 200704   // 50000 int
#define EZ_OFF      401408   // 64*128 float
#define IZ_OFF      434176   // 64*128 float
#define CNT_OFF     466944   // 64 int
#define ZERO_BYTES  467200
#define WB_OFF      467200   // 4 convs * 32768 ushort = 256 KB (B fragments)
#define WCOL_OFF    729344   // 4 * 128 float

typedef short  short8 __attribute__((ext_vector_type(8)));
typedef float  f32x4  __attribute__((ext_vector_type(4)));

union S8 { short8 s; unsigned int u[4]; };

__device__ __forceinline__ unsigned short bf16h(float f) {
  unsigned int u = __float_as_uint(f);
  u += 0x7FFFu + ((u >> 16) & 1u);            // RNE
  return (unsigned short)(u >> 16);
}
__device__ __forceinline__ float bf16tof(unsigned short h) {
  return __uint_as_float(((unsigned int)h) << 16);
}
// packed 2xf32 -> 2xbf16 (v_cvt_pk_bf16_f32): a in low 16, b in high 16
__device__ __forceinline__ unsigned int pk_bf16(float a, float b) {
  __hip_bfloat162 h = __float22bfloat162_rn(make_float2(a, b));
  unsigned int u;
  __builtin_memcpy(&u, &h, 4);
  return u;
}

// -------------------------------------------------------------------------
// ONE aux dispatch (unchanged — all pieces measured small):
//  [0,391):    ext edge-degree histogram (softmax([E,1])==1 -> counts)
//  [391,587):  int edge-degree histogram
//  [587,600):  batch histogram (sorted -> LDS-privatized)
//  [600,608):  W -> MFMA B-fragment prep (hi/lo split-bf16), LDS-staged
// -------------------------------------------------------------------------
#define AB_EXT 391
#define AB_INT 196
#define AB_BAT 13
#define AB_PRE 8

__global__ __launch_bounds__(256) void aux_kernel(
    const int4* __restrict__ ei4, const int4* __restrict__ iei4,
    const int* __restrict__ batch,
    const float* __restrict__ wu_e1, const float* __restrict__ wu_e2,
    const float* __restrict__ wu_i1, const float* __restrict__ wu_i2,
    int* __restrict__ deg_ext, int* __restrict__ deg_int, int* __restrict__ cnt,
    unsigned short* __restrict__ WB, float* __restrict__ wcolp)
{
  __shared__ float WS[64 * 129];
  __shared__ int   hb[64];
  const int b = blockIdx.x, t = threadIdx.x;

  if (b < AB_EXT) {
    const int base = b * 512 + t;
    #pragma unroll
    for (int u = 0; u < 2; ++u) {
      const int i = base + u * 256;
      if (i < NE / 4) {
        const int4 v = ei4[i];
        atomicAdd(&deg_ext[v.x], 1);
        atomicAdd(&deg_ext[v.y], 1);
        atomicAdd(&deg_ext[v.z], 1);
        atomicAdd(&deg_ext[v.w], 1);
      }
    }
  } else if (b < AB_EXT + AB_INT) {
    const int base = (b - AB_EXT) * 512 + t;
    #pragma unroll
    for (int u = 0; u < 2; ++u) {
      const int i = base + u * 256;
      if (i < NEI / 4) {
        const int4 v = iei4[i];
        atomicAdd(&deg_int[v.x], 1);
        atomicAdd(&deg_int[v.y], 1);
        atomicAdd(&deg_int[v.z], 1);
        atomicAdd(&deg_int[v.w], 1);
      }
    }
  } else if (b < AB_EXT + AB_INT + AB_BAT) {
    if (t < 64) hb[t] = 0;
    __syncthreads();
    const int base = (b - AB_EXT - AB_INT) * 4096 + t;
    for (int u = 0; u < 16; ++u) {
      const int i = base + u * 256;
      if (i < NN) atomicAdd(&hb[batch[i]], 1);
    }
    __syncthreads();
    if (t < 64 && hb[t]) atomicAdd(&cnt[t], hb[t]);
  } else {
    const int pb = b - AB_EXT - AB_INT - AB_BAT;   // 0..7
    const int c  = pb >> 1;                         // conv 0..3
    const int h  = pb & 1;                          // row half
    const float* wu = (c == 0) ? wu_e1 : (c == 1) ? wu_e2 : (c == 2) ? wu_i1 : wu_i2;
    for (int idx = t; idx < 64 * 129; idx += 256)
      WS[idx] = wu[(size_t)h * 64 * 129 + idx];
    __syncthreads();
    const int lane = t & 63, u = t >> 6;
    const int n = lane & 15, quad = lane >> 4;
    const int ct = 4 * h + u;
    unsigned short* wb = WB + c * 32768;
    #pragma unroll
    for (int kc = 0; kc < 4; ++kc) {
      const int k0 = kc * 32 + quad * 8;
      const float* src = &WS[(u * 16 + n) * 129 + k0];
      short8 hi, lo;
      #pragma unroll
      for (int e = 0; e < 8; ++e) {
        const float v = src[e];
        const unsigned short hh = bf16h(v);
        hi[e] = (short)hh;
        lo[e] = (short)bf16h(v - bf16tof(hh));
      }
      const int fbase = ((ct * 4 + kc) * 2) * 512 + lane * 8;
      *(short8*)&wb[fbase]       = hi;
      *(short8*)&wb[fbase + 512] = lo;
    }
    if (t < 64) wcolp[c * 128 + h * 64 + t] = WS[t * 129 + 128];
  }
}

// -------------------------------------------------------------------------
// Fused conv chain — LATENCY-ORIENTED REWRITE (R9).
// Decomposition change: wave w owns ONE 16-col tile (ct = w) across ALL 64
// rows (was: 16 rows x 64 cols).  Consequences:
//   * conv B-slice per wave = 8 fragments (4kc x hi/lo) = 32 VGPR -> hoisted
//     in ONE burst before the staging barrier (conv2's during epilogue1);
//     zero B-load latency inside the MFMA loop (was 32 per-kc L2 loads/conv
//     with 4x cross-wave redundancy).
//   * column scatter reduces fully in-register (+2 shuffles) -> 8 atomic
//     instrs/block fast-path (was 512) — 64x less memory-side atomic traffic.
//   * softmax2 row-sum needs one cross-wave LDS reduction red[64][8].
// XT double-buffered (32 KB): conv1 reads XT[0], E1 written to XT[1] with no
// intervening barrier.  3 barriers total (was 4).
// Numerics identical to R8: A single-bf16, W hi/lo split, deferred softmax-1
// (s1 via ONES-MFMA — each wave's A-fragments span all 128 k, so every wave
// computes its own full row sums; redundant but MFMA is 7% utilized).
// LDS: 34.8 KB -> 4 blocks/CU by LDS; VGPR target <=128 (launch_bounds 512,4).
// -------------------------------------------------------------------------
__global__ __launch_bounds__(512, 4) void conv_mfma_kernel(
    const float* __restrict__ x,
    const int* __restrict__ deg_ext, const int* __restrict__ deg_int,
    const int* __restrict__ batch,
    const unsigned short* __restrict__ WB, const float* __restrict__ wcolp,
    const float* __restrict__ bu_e1, const float* __restrict__ bu_e2,
    const float* __restrict__ bu_i1, const float* __restrict__ bu_i2,
    float* __restrict__ ez_sum, float* __restrict__ iz_sum)
{
  __shared__ unsigned short XT[2][8192];   // A fragments (bf16), 2 x 16 KB
  __shared__ float degs[64];
  __shared__ int   bg[64];
  __shared__ float red[64 * 8];            // [row][wave] softmax2 partials

  const int tid  = threadIdx.x;
  const int lane = tid & 63;
  const int w    = tid >> 6;        // wave = column tile 0..7
  const int n    = lane & 15;
  const int q    = lane >> 4;
  const int mbase = blockIdx.x * 64;
  const int chain = blockIdx.y;

  const int*   deg  = chain ? deg_int : deg_ext;
  float*       gsum = chain ? iz_sum : ez_sum;
  const float* buA  = chain ? bu_i1  : bu_e1;
  const float* buB  = chain ? bu_i2  : bu_e2;
  const int conv1 = chain * 2, conv2 = chain * 2 + 1;
  const int j = w * 16 + n;         // this lane's output column

  const short8 ONES = {0x3F80, 0x3F80, 0x3F80, 0x3F80, 0x3F80, 0x3F80, 0x3F80, 0x3F80};

  // ---- hoist conv1 B-slice (8 fragments) + per-column scalars: all
  //      independent of LDS, issued before the staging barrier.
  short8 B1h[4], B1l[4];
  {
    const unsigned short* p = WB + conv1 * 32768 + (w * 4) * 1024 + lane * 8;
    #pragma unroll
    for (int kc = 0; kc < 4; ++kc) {
      B1h[kc] = *(const short8*)&p[kc * 1024];
      B1l[kc] = *(const short8*)&p[kc * 1024 + 512];
    }
  }
  const float wc1 = wcolp[conv1 * 128 + j];
  const float bs1 = buA[j];

  // ---- stage x -> bf16 A fragments, octet-linear mapping (conflict-free)
  #pragma unroll
  for (int u = 0; u < 2; ++u) {
    const int oct  = u * 512 + tid;          // 1024 octets
    const int frag = oct >> 6, l = oct & 63; // frag = rt_s*4+kc_s, l = qk*16+m
    const int row  = (frag >> 2) * 16 + (l & 15);
    const int k0   = (frag & 3) * 32 + (l >> 4) * 8;
    const int node = mbase + row;
    float4 a = make_float4(0.f, 0.f, 0.f, 0.f), bb = a;
    if (node < NN) {
      const float* xr = x + (size_t)node * FD + k0;
      a  = *(const float4*)xr;
      bb = *(const float4*)(xr + 4);
    }
    S8 hi;
    hi.u[0] = pk_bf16(a.x, a.y);
    hi.u[1] = pk_bf16(a.z, a.w);
    hi.u[2] = pk_bf16(bb.x, bb.y);
    hi.u[3] = pk_bf16(bb.z, bb.w);
    *(short8*)&XT[0][oct * 8] = hi.s;
  }
  if (tid < 64) {
    const int node = mbase + tid;
    degs[tid] = (node < NN) ? (float)deg[node] : 0.f;
    bg[tid]   = (node < NN) ? batch[node] : 0;
  }
  __syncthreads();   // barrier 1: A fragments + degs + bg visible

  // ================= conv1: all 64 rows x cols [16w,16w+16) ===============
  f32x4 acc[4];
  #pragma unroll
  for (int rt = 0; rt < 4; ++rt) acc[rt] = (f32x4){0.f, 0.f, 0.f, 0.f};

  #pragma unroll
  for (int kc = 0; kc < 4; ++kc) {
    #pragma unroll
    for (int rt = 0; rt < 4; ++rt) {
      const short8 Ah = *(const short8*)&XT[0][((rt * 4 + kc) * 64 + lane) * 8];
      f32x4 c = acc[rt];
      c = __builtin_amdgcn_mfma_f32_16x16x32_bf16(Ah, B1h[kc], c, 0, 0, 0);
      c = __builtin_amdgcn_mfma_f32_16x16x32_bf16(Ah, B1l[kc], c, 0, 0, 0);
      acc[rt] = c;
    }
  }

  // ---- hoist conv2 B-slice now: latency hides under epilogue1 + barrier2
  short8 B2h[4], B2l[4];
  {
    const unsigned short* p = WB + conv2 * 32768 + (w * 4) * 1024 + lane * 8;
    #pragma unroll
    for (int kc = 0; kc < 4; ++kc) {
      B2h[kc] = *(const short8*)&p[kc * 1024];
      B2l[kc] = *(const short8*)&p[kc * 1024 + 512];
    }
  }
  const float wc2 = wcolp[conv2 * 128 + j];
  const float bs2 = buB[j];

  // ---- epilogue1: E1 = exp(leaky(acc + bias + deg*wcol))  (unnormalized)
  #pragma unroll
  for (int rt = 0; rt < 4; ++rt) {
    const float4 dg = *(const float4*)&degs[rt * 16 + 4 * q];
    const float dgv[4] = {dg.x, dg.y, dg.z, dg.w};
    #pragma unroll
    for (int r = 0; r < 4; ++r) {
      float v = acc[rt][r] + bs1 + dgv[r] * wc1;
      v = (v > 0.f) ? v : 0.01f * v;
      acc[rt][r] = __expf(v);
    }
  }

  // ---- write E1 (bf16) into XT[1] in A-fragment order:
  // value (row = rt*16+4q+r, col j): kc' = j>>5 = w>>1,
  // lane' = ((w&1)*2 + (n>>3))*16 + (row&15), elem = n&7.
  #pragma unroll
  for (int rt = 0; rt < 4; ++rt) {
    const int ib = ((rt * 4 + (w >> 1)) * 64 + ((w & 1) * 2 + (n >> 3)) * 16 + q * 4) * 8 + (n & 7);
    const unsigned int u01 = pk_bf16(acc[rt][0], acc[rt][1]);
    const unsigned int u23 = pk_bf16(acc[rt][2], acc[rt][3]);
    XT[1][ib]      = (unsigned short)(u01 & 0xFFFFu);
    XT[1][ib + 8]  = (unsigned short)(u01 >> 16);
    XT[1][ib + 16] = (unsigned short)(u23 & 0xFFFFu);
    XT[1][ib + 24] = (unsigned short)(u23 >> 16);
  }
  __syncthreads();   // barrier 2: E1 fragments visible (XT[0] now dead)

  // ================= conv2 (+ s1 via ONES MFMA) =================
  f32x4 acc2[4], s1a[4];
  #pragma unroll
  for (int rt = 0; rt < 4; ++rt) {
    acc2[rt] = (f32x4){0.f, 0.f, 0.f, 0.f};
    s1a[rt]  = (f32x4){0.f, 0.f, 0.f, 0.f};
  }
  #pragma unroll
  for (int kc = 0; kc < 4; ++kc) {
    #pragma unroll
    for (int rt = 0; rt < 4; ++rt) {
      const short8 Ah = *(const short8*)&XT[1][((rt * 4 + kc) * 64 + lane) * 8];
      f32x4 c = acc2[rt];
      c = __builtin_amdgcn_mfma_f32_16x16x32_bf16(Ah, B2h[kc], c, 0, 0, 0);
      c = __builtin_amdgcn_mfma_f32_16x16x32_bf16(Ah, B2l[kc], c, 0, 0, 0);
      acc2[rt] = c;
      s1a[rt]  = __builtin_amdgcn_mfma_f32_16x16x32_bf16(Ah, ONES, s1a[rt], 0, 0, 0);
    }
  }

  // ---- epilogue2: logits2 = U2/s1 + deg*wc + b; E2 = exp(leaky(.));
  //      cross-wave row partials into red[row][w]
  #pragma unroll
  for (int rt = 0; rt < 4; ++rt) {
    const float4 dg = *(const float4*)&degs[rt * 16 + 4 * q];
    const float dgv[4] = {dg.x, dg.y, dg.z, dg.w};
    #pragma unroll
    for (int r = 0; r < 4; ++r) {
      float u2 = acc2[rt][r] * (1.0f / s1a[rt][r]) + bs2 + dgv[r] * wc2;
      u2 = (u2 > 0.f) ? u2 : 0.01f * u2;
      acc2[rt][r] = __expf(u2);
    }
    #pragma unroll
    for (int r = 0; r < 4; ++r) {
      float t = acc2[rt][r];
      t += __shfl_xor(t, 1);
      t += __shfl_xor(t, 2);
      t += __shfl_xor(t, 4);
      t += __shfl_xor(t, 8);
      if (n == 0) red[(rt * 16 + q * 4 + r) * 8 + w] = t;
    }
  }
  __syncthreads();   // barrier 3: row partials visible

  // ---- normalize (softmax2 denominator = sum of 8 wave-partials per row)
  #pragma unroll
  for (int rt = 0; rt < 4; ++rt) {
    #pragma unroll
    for (int r = 0; r < 4; ++r) {
      const int row = rt * 16 + q * 4 + r;
      const f32x4 ra = *(const f32x4*)&red[row * 8];
      const f32x4 rb = *(const f32x4*)&red[row * 8 + 4];
      const float rs = ((ra[0] + ra[1]) + (ra[2] + ra[3]))
                     + ((rb[0] + rb[1]) + (rb[2] + rb[3]));
      acc2[rt][r] *= (1.0f / rs);
    }
  }

  // ---- scatter into per-graph sums (batch sorted: one-graph fast path)
  {
    bool fast = false; int gall = 0;
    if (mbase + 63 < NN) { gall = bg[0]; fast = (bg[63] == gall); }
    if (fast) {
      float s = 0.f;
      #pragma unroll
      for (int rt = 0; rt < 4; ++rt)
        #pragma unroll
        for (int r = 0; r < 4; ++r) s += acc2[rt][r];
      s += __shfl_xor(s, 16);
      s += __shfl_xor(s, 32);
      if (q == 0) atomicAdd(&gsum[gall * FD + j], s);   // 1 instr/wave, 16 lanes
    } else {
      #pragma unroll
      for (int rt = 0; rt < 4; ++rt)
        #pragma unroll
        for (int r = 0; r < 4; ++r) {
          const int row = rt * 16 + q * 4 + r;
          if (mbase + row < NN)
            atomicAdd(&gsum[bg[row] * FD + j], acc2[rt][r]);
        }
    }
  }
}

// -------------------------------------------------------------------------
// Final MLP: 64 blocks (one per graph) x 128 threads.
// -------------------------------------------------------------------------
__global__ __launch_bounds__(128) void fc_kernel(
    const float* __restrict__ ez_sum, const float* __restrict__ iz_sum,
    const int* __restrict__ cnt,
    const float* __restrict__ fc1_w, const float* __restrict__ fc1_b,
    const float* __restrict__ fc2_w, const float* __restrict__ fc2_b,
    float* __restrict__ out)
{
  __shared__ float z[256];
  __shared__ float red2[2];
  const int g = blockIdx.x, t = threadIdx.x;
  const float denom = fmaxf((float)cnt[g], 1.0f);
  z[t]       = ez_sum[g * 128 + t] / denom;
  z[128 + t] = iz_sum[g * 128 + t] / denom;
  __syncthreads();

  const float* wr = fc1_w + (size_t)t * 256;
  float a = fc1_b[t];
  #pragma unroll 4
  for (int c = 0; c < 256; c += 4) {
    const float4 wv = *(const float4*)(wr + c);
    a += wv.x * z[c] + wv.y * z[c + 1] + wv.z * z[c + 2] + wv.w * z[c + 3];
  }
  a = fmaxf(a, 0.f) * fc2_w[t];
  a += __shfl_xor(a, 1);
  a += __shfl_xor(a, 2);
  a += __shfl_xor(a, 4);
  a += __shfl_xor(a, 8);
  a += __shfl_xor(a, 16);
  a += __shfl_xor(a, 32);
  if ((t & 63) == 0) red2[t >> 6] = a;
  __syncthreads();
  if (t == 0) out[g] = red2[0] + red2[1] + fc2_b[0];
}

// -------------------------------------------------------------------------
extern "C" void kernel_launch(void* const* d_in, const int* in_sizes, int n_in,
                              void* d_out, int out_size, void* d_ws, size_t ws_size,
                              hipStream_t stream) {
  const float* x     = (const float*)d_in[0];
  const int4*  ei4   = (const int4*) d_in[1];   // [2,E]: first E = sources
  const int4*  iei4  = (const int4*) d_in[3];
  const int*   batch = (const int*)  d_in[5];
  const float* wu_e1 = (const float*)d_in[8];
  const float* bu_e1 = (const float*)d_in[9];
  const float* wu_e2 = (const float*)d_in[12];
  const float* bu_e2 = (const float*)d_in[13];
  const float* wu_i1 = (const float*)d_in[16];
  const float* bu_i1 = (const float*)d_in[17];
  const float* wu_i2 = (const float*)d_in[20];
  const float* bu_i2 = (const float*)d_in[21];
  const float* fc1_w = (const float*)d_in[22];
  const float* fc1_b = (const float*)d_in[23];
  const float* fc2_w = (const float*)d_in[24];
  const float* fc2_b = (const float*)d_in[25];

  char* ws = (char*)d_ws;
  int*   deg_ext = (int*)  (ws + DEG_EXT_OFF);
  int*   deg_int = (int*)  (ws + DEG_INT_OFF);
  float* ez      = (float*)(ws + EZ_OFF);
  float* iz      = (float*)(ws + IZ_OFF);
  int*   cnt     = (int*)  (ws + CNT_OFF);
  unsigned short* WB = (unsigned short*)(ws + WB_OFF);
  float* wcolp   = (float*)(ws + WCOL_OFF);

  hipMemsetAsync(d_ws, 0, ZERO_BYTES, stream);

  aux_kernel<<<AB_EXT + AB_INT + AB_BAT + AB_PRE, 256, 0, stream>>>(
      ei4, iei4, batch, wu_e1, wu_e2, wu_i1, wu_i2,
      deg_ext, deg_int, cnt, WB, wcolp);

  conv_mfma_kernel<<<dim3((NN + 63) / 64, 2), 512, 0, stream>>>(
      x, deg_ext, deg_int, batch, WB, wcolp,
      bu_e1, bu_e2, bu_i1, bu_i2, ez, iz);

  fc_kernel<<<NG, 128, 0, stream>>>(ez, iz, cnt, fc1_w, fc1_b, fc2_w, fc2_b,
                                    (float*)d_out);
}